// Round 14
// baseline (3118.433 us; speedup 1.0000x reference)
//
#include <hip/hip_runtime.h>
#include <math.h>

typedef _Float16 f16;
typedef f16 f16x8 __attribute__((ext_vector_type(8)));
typedef f16 f16x4 __attribute__((ext_vector_type(4)));
typedef float f32x4 __attribute__((ext_vector_type(4)));
typedef unsigned int u32;
typedef unsigned long long u64;

#define TT 64
#define DD 768
#define MR 1024
#define ALPHAF 0.4f
#define NWG 120
#define GRID 240
#define LMN 50257
#define LMK 768

__device__ __forceinline__ float geluf(float x){
  return 0.5f*x*(1.0f + erff(x*0.70710678118654752f));
}

// ---- coherent (agent-scope, LLC) accessors ----
__device__ __forceinline__ u64 ld_a64(const void* p){
  return __hip_atomic_load((const u64*)p, __ATOMIC_RELAXED, __HIP_MEMORY_SCOPE_AGENT);
}
__device__ __forceinline__ f16x8 ld_act16h(const f16* p){
  union { u64 u[2]; f16x8 v; } c;
  c.u[0] = ld_a64(p); c.u[1] = ld_a64(p + 4); return c.v;
}
__device__ __forceinline__ float2 ld_actf2(const float* p){
  union { u64 u; float2 f; } c; c.u = ld_a64(p); return c.f;
}
__device__ __forceinline__ float ld_actf(const float* p){
  union { u32 u; float f; } c;
  c.u = __hip_atomic_load((const u32*)p, __ATOMIC_RELAXED, __HIP_MEMORY_SCOPE_AGENT);
  return c.f;
}
__device__ __forceinline__ void st_actf(float* p, float v){
  union { u32 u; float f; } c; c.f = v;
  __hip_atomic_store((u32*)p, c.u, __ATOMIC_RELAXED, __HIP_MEMORY_SCOPE_AGENT);
}
__device__ __forceinline__ void st_acth(f16* p, float v){
  union { unsigned short u; f16 h; } c; c.h = (f16)v;
  __hip_atomic_store((unsigned short*)p, c.u, __ATOMIC_RELAXED, __HIP_MEMORY_SCOPE_AGENT);
}

// ---- encoder phase barrier ----
__device__ __forceinline__ void egbar(int* ef, int ep){
  __syncthreads();
  if (threadIdx.x == 0){
    __threadfence();
    __hip_atomic_store(ef + blockIdx.x*32, ep, __ATOMIC_RELAXED, __HIP_MEMORY_SCOPE_AGENT);
  }
  {
    int id = threadIdx.x; bool active = id < GRID;
    const int* fp = ef + id*32;
    while (true){
      int v = active ? __hip_atomic_load(fp, __ATOMIC_RELAXED, __HIP_MEMORY_SCOPE_AGENT) : ep;
      if (__ballot(v >= ep) == ~0ull) break;
      __builtin_amdgcn_s_sleep(1);
    }
  }
  __syncthreads();
  if (threadIdx.x == 0) __threadfence();
  __syncthreads();
}

// ---- scan flag primitives ----
__device__ __forceinline__ void postf(int* f, int ep){
  asm volatile("s_waitcnt vmcnt(0)" ::: "memory");
  __syncthreads();
  if (threadIdx.x == 0)
    __hip_atomic_store(f, ep, __ATOMIC_RELAXED, __HIP_MEMORY_SCOPE_AGENT);
}
__device__ __forceinline__ void waitf(const int* f, int n, int ep){
  if (threadIdx.x < 64){
    int lane = threadIdx.x;
    while (true){
      bool ok = true;
      for (int i = lane; i < n; i += 64){
        if (__hip_atomic_load(f + i*32, __ATOMIC_RELAXED, __HIP_MEMORY_SCOPE_AGENT) < ep){
          ok = false; break;
        }
      }
      if (__ballot(ok) == ~0ull) break;
      __builtin_amdgcn_s_sleep(1);
    }
  }
  __syncthreads();
}

__device__ __forceinline__ void red_store(float* rb, int lane, f32x4 a){
  rb[lane] = a[0]; rb[64+lane] = a[1]; rb[128+lane] = a[2]; rb[192+lane] = a[3];
}
__device__ __forceinline__ f32x4 red_sum4(float rb[4][256], int lane){
  f32x4 s;
  #pragma unroll
  for (int r = 0; r < 4; r++)
    s[r] = rb[0][r*64+lane] + rb[1][r*64+lane] + rb[2][r*64+lane] + rb[3][r*64+lane];
  return s;
}
__device__ __forceinline__ f32x4 red_sum2(float rb[4][256], int lane, int w0, int w1){
  f32x4 s;
  #pragma unroll
  for (int r = 0; r < 4; r++)
    s[r] = rb[w0][r*64+lane] + rb[w1][r*64+lane];
  return s;
}

// ---- device phase helpers ----
__device__ void dev_ln(const float* xr, const float* g, const float* b,
                       float* outr, float* outTr, float* red, bool l2n){
  int tid = threadIdx.x, lane = tid & 63, wid = tid >> 6;
  float v[3]; float s = 0.f, ss = 0.f;
  #pragma unroll
  for (int j = 0; j < 3; j++){ float t0 = xr[tid + j*256]; v[j] = t0; s += t0; ss += t0*t0; }
  #pragma unroll
  for (int o = 1; o < 64; o <<= 1){ s += __shfl_xor(s, o); ss += __shfl_xor(ss, o); }
  if (lane == 0){ red[wid] = s; red[4+wid] = ss; }
  __syncthreads();
  s  = red[0]+red[1]+red[2]+red[3];
  ss = red[4]+red[5]+red[6]+red[7];
  float mean = s*(1.f/768.f);
  float var  = ss*(1.f/768.f) - mean*mean;
  float rstd = rsqrtf(var + 1e-5f);
  float y[3];
  #pragma unroll
  for (int j = 0; j < 3; j++){ int n = tid + j*256; y[j] = (v[j]-mean)*rstd*g[n] + b[n]; }
  if (l2n){
    float n2 = y[0]*y[0] + y[1]*y[1] + y[2]*y[2];
    #pragma unroll
    for (int o = 1; o < 64; o <<= 1) n2 += __shfl_xor(n2, o);
    __syncthreads();
    if (lane == 0) red[wid] = n2;
    __syncthreads();
    n2 = red[0]+red[1]+red[2]+red[3];
    float inv = 1.f / fmaxf(sqrtf(n2), 1e-12f);
    y[0] *= inv; y[1] *= inv; y[2] *= inv;
  }
  #pragma unroll
  for (int j = 0; j < 3; j++) outr[tid + j*256] = y[j];
  if (outTr){
    #pragma unroll
    for (int j = 0; j < 3; j++) outTr[tid + j*256] = y[j];
  }
  __syncthreads();
}

// 128x128 GEMM tile, software-pipelined (double-buffered LDS + reg prefetch)
__device__ void dev_gemm_tile(char* lds, const float* A, int lda,
    const float* Bw, int ldb, int nrb, int N, int K, int m0, int n0,
    const float* bias, const float* res, float* outF, f16* outH,
    float scale, int act, int operm)
{
  int tid = threadIdx.x;
  int lane = tid & 63, wid = tid >> 6;
  int wr = (wid >> 1)*64, wc = (wid & 1)*64;
  int l15 = lane & 15, kb = lane >> 4;
  f32x4 acc[4][4];
  #pragma unroll
  for (int i = 0; i < 4; i++)
    #pragma unroll
    for (int j = 0; j < 4; j++){ f32x4 z = {0.f,0.f,0.f,0.f}; acc[i][j] = z; }
  int rA = tid >> 3;
  int k4 = (tid & 7)*4;
  float4 va[4], vb[4];
  #pragma unroll
  for (int it = 0; it < 4; ++it){
    int r = it*32 + rA;
    va[it] = *(const float4*)(A + (size_t)(m0+r)*lda + k4);
    int rB = n0 + r;
    if (rB < nrb) vb[it] = *(const float4*)(Bw + (size_t)rB*ldb + k4);
    else { vb[it].x=0.f; vb[it].y=0.f; vb[it].z=0.f; vb[it].w=0.f; }
  }
  for (int kk = 0; kk < K; kk += 32){
    char* cb = lds + (((kk >> 5) & 1) ? 20480 : 0);
    f16 (*As)[40] = (f16(*)[40])cb;
    f16 (*Bs)[40] = (f16(*)[40])(cb + 10240);
    #pragma unroll
    for (int it = 0; it < 4; ++it){
      int r = it*32 + rA;
      *(f16x4*)(&As[r][k4]) = (f16x4){(f16)va[it].x,(f16)va[it].y,(f16)va[it].z,(f16)va[it].w};
      *(f16x4*)(&Bs[r][k4]) = (f16x4){(f16)vb[it].x,(f16)vb[it].y,(f16)vb[it].z,(f16)vb[it].w};
    }
    __syncthreads();
    if (kk + 32 < K){
      #pragma unroll
      for (int it = 0; it < 4; ++it){
        int r = it*32 + rA;
        va[it] = *(const float4*)(A + (size_t)(m0+r)*lda + kk + 32 + k4);
        int rB = n0 + r;
        if (rB < nrb) vb[it] = *(const float4*)(Bw + (size_t)rB*ldb + kk + 32 + k4);
        else { vb[it].x=0.f; vb[it].y=0.f; vb[it].z=0.f; vb[it].w=0.f; }
      }
    }
    f16x8 af[4], bfv[4];
    #pragma unroll
    for (int i = 0; i < 4; i++) af[i]  = *(const f16x8*)(&As[wr + i*16 + l15][kb*8]);
    #pragma unroll
    for (int j = 0; j < 4; j++) bfv[j] = *(const f16x8*)(&Bs[wc + j*16 + l15][kb*8]);
    #pragma unroll
    for (int i = 0; i < 4; i++)
      #pragma unroll
      for (int j = 0; j < 4; j++)
        acc[i][j] = __builtin_amdgcn_mfma_f32_16x16x32_f16(af[i], bfv[j], acc[i][j], 0, 0, 0);
  }
  __syncthreads();
  #pragma unroll
  for (int i = 0; i < 4; i++){
    #pragma unroll
    for (int j = 0; j < 4; j++){
      #pragma unroll
      for (int r = 0; r < 4; r++){
        int m = m0 + wr + i*16 + kb*4 + r;
        int n = n0 + wc + j*16 + l15;
        if (n < N){
          float v = acc[i][j][r]*scale;
          if (bias) v += bias[n];
          if (act == 1) v = geluf(v);
          if (res) v += res[(size_t)m*N + n];
          size_t off;
          if (operm == 0) off = (size_t)m*N + n;
          else            off = ((size_t)(m & 63)*16 + (m >> 6))*N + n;
          if (outF) outF[off] = v;
          if (outH) outH[off] = (f16)v;
        }
      }
    }
  }
}

__device__ void dev_attn(char* lds, const float* qkv, float* o, int bh){
  float (*kv)[96] = (float(*)[96])lds;
  float (*sm)[68] = (float(*)[68])(lds + 24576);
  int b = bh >> 3, h = bh & 7;
  int tid = threadIdx.x;
  const float* base = qkv + (size_t)b*64*2304 + h*96;
  for (int idx = tid; idx < 64*96; idx += 256){ int i = idx/96, d = idx - i*96;
    kv[i][d] = base[(size_t)i*2304 + 768 + d]; }
  __syncthreads();
  {
    int i = tid >> 2;
    const float* q = base + (size_t)i*2304;
    int j0 = (tid & 3)*16;
    for (int jj = 0; jj < 16; jj++){
      int j = j0 + jj;
      float sv = -1e30f;
      if (j <= i){ float acc = 0.f;
        for (int d = 0; d < 96; d++) acc += q[d]*kv[j][d];
        sv = acc*0.10206207261596576f; }
      sm[i][j] = sv;
    }
  }
  __syncthreads();
  for (int idx = tid; idx < 64*96; idx += 256){ int i = idx/96, d = idx - i*96;
    kv[i][d] = base[(size_t)i*2304 + 1536 + d]; }
  if (tid < 64){
    int i = tid;
    float mx = -1e30f;
    for (int j = 0; j <= i; j++) mx = fmaxf(mx, sm[i][j]);
    float sum = 0.f;
    for (int j = 0; j <= i; j++){ float e = expf(sm[i][j]-mx); sm[i][j] = e; sum += e; }
    float inv = 1.f/sum;
    for (int j = 0; j <= i; j++) sm[i][j] *= inv;
  }
  __syncthreads();
  for (int idx = tid; idx < 64*96; idx += 256){
    int i = idx/96, d = idx - i*96;
    float acc = 0.f;
    for (int j = 0; j <= i; j++) acc += sm[i][j]*kv[j][d];
    o[(size_t)(b*64+i)*768 + h*96 + d] = acc;
  }
  __syncthreads();
}

__device__ void dev_tr_f(char* lds, const float* in, float* out, int R, int C, int bx, int by){
  float (*tile)[33] = (float(*)[33])lds;
  int r0 = by*32, c0 = bx*32;
  int tx = threadIdx.x & 31, ty = threadIdx.x >> 5;
  #pragma unroll
  for (int i = 0; i < 32; i += 8) tile[ty+i][tx] = in[(size_t)(r0+ty+i)*C + (c0+tx)];
  __syncthreads();
  #pragma unroll
  for (int i = 0; i < 32; i += 8) out[(size_t)(c0+ty+i)*R + (r0+tx)] = tile[tx][ty+i];
  __syncthreads();
}
__device__ void dev_tr_h(char* lds, const float* in, f16* out, int R, int C, int bx, int by){
  float (*tile)[33] = (float(*)[33])lds;
  int r0 = by*32, c0 = bx*32;
  int tx = threadIdx.x & 31, ty = threadIdx.x >> 5;
  #pragma unroll
  for (int i = 0; i < 32; i += 8) tile[ty+i][tx] = in[(size_t)(r0+ty+i)*C + (c0+tx)];
  __syncthreads();
  #pragma unroll
  for (int i = 0; i < 32; i += 8) out[(size_t)(c0+ty+i)*R + (r0+tx)] = (f16)tile[tx][ty+i];
  __syncthreads();
}

__global__ void k_init(int* flags){
  for (int i = threadIdx.x; i < 512*32; i += 256) flags[i] = 0;
}

// =================== MEGA KERNEL ===================
__global__ __launch_bounds__(256, 1) void k_all(
  const int* tok, const float* emb, const float* pos,
  const float* aiw, const float* aib, const float* aow, const float* aob,
  const float* fw1, const float* fb1, const float* fw2, const float* fb2,
  const float* n1g, const float* n1b, const float* n2g, const float* n2b,
  const float* eng, const float* enb,
  const float* V0, const float* b0, const float* V1, const float* b1,
  const float* cw1, const float* cb1, const float* cw2, const float* cb2,
  const float* gw, const float* gb_, const float* tw, const float* Rm,
  const float* og, const float* ob, const float* lmw,
  float* x, float* xn, float* qkv, float* o_, float* mid,
  float* ctx, float* ctxT, float* V0t, float* cw2t,
  float* ctxV0T, float* gctxT, float* bdg,
  f16* WAf, f16* V1tf, f16* Wc1f, f16* WDf, f16* lmw16,
  f16* hf, f16* h1f, f16* c1f, f16* gcaf,
  float* val, float* pp, float* tfs, int* flags, float* out)
{
  __shared__ __align__(16) char smem[147456];
  __shared__ float redbuf[4][256];
  __shared__ float normp[4][16];
  __shared__ float red[8];
  const int tid = threadIdx.x, lane = tid & 63, wid = tid >> 6;
  const int bid = blockIdx.x;
  const int l15 = lane & 15, kb = lane >> 4;
  int* afl = flags;
  int* bfl = flags + 120*32;
  int* cfl = flags + 168*32;
  int* dfl = flags + 192*32;
  int* mfl = flags + 240*32;
  int* encf = flags + 256*32;
  int eep = 0;

  // ===== P0: embed =====
  for (int m = bid; m < MR; m += GRID){
    int t = m & 63; int id = tok[m];
    const float* e = emb + (size_t)id*DD;
    const float* p = pos + (size_t)t*DD;
    float* xr = x + (size_t)m*DD;
    for (int j = tid; j < DD; j += 256) xr[j] = e[j] + p[j];
  }
  egbar(encf, ++eep);

  // ===== encoder layers =====
  for (int l = 0; l < 2; l++){
    for (int m = bid; m < MR; m += GRID)
      dev_ln(x + (size_t)m*DD, n1g + l*DD, n1b + l*DD, xn + (size_t)m*DD, nullptr, red, false);
    egbar(encf, ++eep);
    for (int tl = bid; tl < 144; tl += GRID)
      dev_gemm_tile(smem, xn, 768, aiw + (size_t)l*2304*768, 768, 2304, 2304, 768,
                    (tl % 8)*128, (tl / 8)*128, aib + l*2304, nullptr, qkv, nullptr, 1.f, 0, 0);
    egbar(encf, ++eep);
    for (int u = bid; u < 128; u += GRID) dev_attn(smem, qkv, o_, u);
    egbar(encf, ++eep);
    for (int tl = bid; tl < 48; tl += GRID)
      dev_gemm_tile(smem, o_, 768, aow + (size_t)l*768*768, 768, 768, 768, 768,
                    (tl % 8)*128, (tl / 8)*128, aob + l*768, x, x, nullptr, 1.f, 0, 0);
    egbar(encf, ++eep);
    for (int m = bid; m < MR; m += GRID)
      dev_ln(x + (size_t)m*DD, n2g + l*DD, n2b + l*DD, xn + (size_t)m*DD, nullptr, red, false);
    egbar(encf, ++eep);
    for (int tl = bid; tl < 128; tl += GRID)
      dev_gemm_tile(smem, xn, 768, fw1 + (size_t)l*2048*768, 768, 2048, 2048, 768,
                    (tl % 8)*128, (tl / 8)*128, fb1 + l*2048, nullptr, mid, nullptr, 1.f, 1, 0);
    egbar(encf, ++eep);
    for (int tl = bid; tl < 48; tl += GRID)
      dev_gemm_tile(smem, mid, 2048, fw2 + (size_t)l*768*2048, 2048, 768, 768, 2048,
                    (tl % 8)*128, (tl / 8)*128, fb2 + l*768, x, x, nullptr, 1.f, 0, 0);
    egbar(encf, ++eep);
  }
  for (int m = bid; m < MR; m += GRID)
    dev_ln(x + (size_t)m*DD, eng, enb, ctx + (size_t)m*DD,
           ctxT + ((size_t)(m & 63)*16 + (m >> 6))*DD, red, true);
  egbar(encf, ++eep);

  // ===== P17: transposes + small casts + bdg =====
  for (int task = bid; task < 5184; task += GRID){
    if (task < 2304)      dev_tr_f(smem, V0, V0t, 768, 3072, task % 96, task / 96);
    else if (task < 2880){ int t2 = task - 2304; dev_tr_f(smem, cw2, cw2t, 768, 768, t2 % 24, t2 / 24); }
    else                 { int t2 = task - 2880; dev_tr_h(smem, V1, V1tf, 3072, 768, t2 % 24, t2 / 24); }
  }
  {
    const int g0 = bid*256 + tid, stride = GRID*256;
    for (int i = g0; i < 73728; i += stride){
      float4 a = ((const float4*)cw1)[i*2]; float4 b2 = ((const float4*)cw1)[i*2+1];
      ((f16x8*)Wc1f)[i] = (f16x8){(f16)a.x,(f16)a.y,(f16)a.z,(f16)a.w,(f16)b2.x,(f16)b2.y,(f16)b2.z,(f16)b2.w};
    }
    for (int i = g0; i < 73728; i += stride){
      float4 a = ((const float4*)cw2)[i*2]; float4 b2 = ((const float4*)cw2)[i*2+1];
      ((f16x8*)WDf)[i] = (f16x8){(f16)a.x,(f16)a.y,(f16)a.z,(f16)a.w,(f16)b2.x,(f16)b2.y,(f16)b2.z,(f16)b2.w};
    }
    for (int g = g0; g < 768; g += stride){
      const float* row = gw + (size_t)g*1536 + 768;
      float s = 0.f;
      for (int j = 0; j < 768; j++) s += cb2[j]*row[j];
      bdg[g] = s;
    }
  }
  egbar(encf, ++eep);

  // ===== P18: precompute GEMMs =====
  for (int task = bid; task < 456; task += GRID){
    if (task < 144)
      dev_gemm_tile(smem, V0t, 768, Rm, 768, 768, 768, 768,
                    (task % 24)*128, (task / 24)*128, nullptr, nullptr, nullptr, WAf, ALPHAF, 0, 0);
    else if (task < 180){ int t2 = task - 144;
      dev_gemm_tile(smem, tw, 768, Rm, 768, 768, 768, 768,
                    (t2 % 6)*128, (t2 / 6)*128, nullptr, nullptr, nullptr, WAf + (size_t)3072*768, ALPHAF, 0, 0); }
    else if (task < 372){ int t2 = task - 180;
      dev_gemm_tile(smem, ctx, 768, V0t, 768, 3072, 3072, 768,
                    (t2 % 8)*128, (t2 / 8)*128, b0, nullptr, ctxV0T, nullptr, 1.f, 0, 1); }
    else if (task < 420){ int t2 = task - 372;
      dev_gemm_tile(smem, ctx, 768, gw, 1536, 768, 768, 768,
                    (t2 % 8)*128, (t2 / 8)*128, nullptr, nullptr, gctxT, nullptr, 1.f, 0, 1); }
    else { int t2 = task - 420;
      dev_gemm_tile(smem, gw + 768, 1536, cw2t, 768, 768, 768, 768,
                    (t2 % 6)*128, (t2 / 6)*128, nullptr, nullptr, nullptr, WDf + (size_t)768*768, 1.f, 0, 0); }
  }
  egbar(encf, ++eep);

  // ===================== consumers (bids 120..239) =====================
  if (bid >= NWG){
    const int lw = bid - NWG;
    const int wr = (wid >> 1)*64, wc = (wid & 1)*64;
    // private lmw cast (own GEMM tiles)
    for (int nt = lw; nt < 393; nt += 120){
      int r0 = nt*128;
      int rend = r0 + 128; if (rend > LMN) rend = LMN;
      int u0 = r0*96, u1 = rend*96;
      for (int i = u0 + tid; i < u1; i += 256){
        float4 a = ((const float4*)lmw)[(size_t)i*2];
        float4 b2 = ((const float4*)lmw)[(size_t)i*2+1];
        ((f16x8*)lmw16)[i] = (f16x8){(f16)a.x,(f16)a.y,(f16)a.z,(f16)a.w,
                                     (f16)b2.x,(f16)b2.y,(f16)b2.z,(f16)b2.w};
      }
    }
    __syncthreads();

    if (lw < 16){
      // combine duty (row m=lw) each step, interleaved with chunk GEMM every 8 steps
      const int m = lw;
      for (int t = 0; t < TT; ++t){
        waitf(dfl, 48, t+1);
        const int slot = t & 3;
        if (tid < 64){
          float s = 0.f, ss = 0.f;
          if (lane < 48){
            float2 v2 = ld_actf2(pp + slot*1536 + m*96 + lane*2);
            s = v2.x; ss = v2.y;
          }
          #pragma unroll
          for (int o2 = 1; o2 < 64; o2 <<= 1){ s += __shfl_xor(s, o2); ss += __shfl_xor(ss, o2); }
          if (lane == 0){ red[0] = s; red[1] = ss; }
        }
        __syncthreads();
        float mean = red[0]*(1.f/768.f);
        float rstd = rsqrtf(red[1]*(1.f/768.f) - mean*mean + 1e-5f);
        #pragma unroll
        for (int j = 0; j < 3; j++){
          int n = tid + j*256;
          float v = ld_actf(val + slot*12288 + m*768 + n);
          float y = (v - mean)*rstd*og[n] + ob[n];
          y = fminf(5.f, fmaxf(-5.f, y));
          st_acth(hf + ((size_t)m*TT + t)*DD + n, y);
        }
        postf(mfl + m*32, t+1);
        if ((t & 7) == 7){
          int q = t >> 3;
          waitf(mfl, 16, t+1);
          size_t arow[4];
          #pragma unroll
          for (int i = 0; i < 4; i++){
            int rl = wr + i*16 + l15;
            arow[i] = ((size_t)(rl >> 3)*TT + q*8 + (rl & 7))*DD + kb*8;
          }
          for (int nt = lw; nt < 393; nt += 120){
            int n0 = nt*128;
            size_t brow[4];
            #pragma unroll
            for (int j = 0; j < 4; j++){
              int n = n0 + wc + j*16 + l15;
              if (n > LMN-1) n = LMN-1;
              brow[j] = (size_t)n*LMK + kb*8;
            }
            f32x4 acc[4][4];
            #pragma unroll
            for (int i = 0; i < 4; i++)
              #pragma unroll
              for (int j = 0; j < 4; j++){ f32x4 z = {0.f,0.f,0.f,0.f}; acc[i][j] = z; }
            #pragma unroll 4
            for (int kk = 0; kk < LMK; kk += 32){
              f16x8 af[4], bf[4];
              #pragma unroll
              for (int i = 0; i < 4; i++) af[i] = ld_act16h(hf + arow[i] + kk);
              #pragma unroll
              for (int j = 0; j < 4; j++) bf[j] = *(const f16x8*)(lmw16 + brow[j] + kk);
              #pragma unroll
              for (int i = 0; i < 4; i++)
                #pragma unroll
                for (int j = 0; j < 4; j++)
                  acc[i][j] = __builtin_amdgcn_mfma_f32_16x16x32_f16(af[i], bf[j], acc[i][j], 0, 0, 0);
            }
            #pragma unroll
            for (int i = 0; i < 4; i++)
              #pragma unroll
              for (int j = 0; j < 4; j++)
                #pragma unroll
                for (int r = 0; r < 4; r++){
                  int ml = wr + i*16 + kb*4 + r;
                  int b = ml >> 3, tt2 = q*8 + (ml & 7);
                  int n = n0 + wc + j*16 + l15;
                  if (n < LMN) out[((size_t)b*TT + tt2)*LMN + n] = acc[i][j][r];
                }
          }
        }
      }
    } else {
      for (int q = 0; q < 8; ++q){
        waitf(mfl, 16, q*8 + 8);
        size_t arow[4];
        #pragma unroll
        for (int i = 0; i < 4; i++){
          int rl = wr + i*16 + l15;
          arow[i] = ((size_t)(rl >> 3)*TT + q*8 + (rl & 7))*DD + kb*8;
        }
        for (int nt = lw; nt < 393; nt += 120){
          int n0 = nt*128;
          size_t brow[4];
          #pragma unroll
          for (int j = 0; j < 4; j++){
            int n = n0 + wc + j*16 + l15;
            if (n > LMN-1) n = LMN-1;
            brow[j] = (size_t)n*LMK + kb*8;
          }
          f32x4 acc[4][4];
          #pragma unroll
          for (int i = 0; i < 4; i++)
            #pragma unroll
            for (int j = 0; j < 4; j++){ f32x4 z = {0.f,0.f,0.f,0.f}; acc[i][j] = z; }
          #pragma unroll 4
          for (int kk = 0; kk < LMK; kk += 32){
            f16x8 af[4], bf[4];
            #pragma unroll
            for (int i = 0; i < 4; i++) af[i] = ld_act16h(hf + arow[i] + kk);
            #pragma unroll
            for (int j = 0; j < 4; j++) bf[j] = *(const f16x8*)(lmw16 + brow[j] + kk);
            #pragma unroll
            for (int i = 0; i < 4; i++)
              #pragma unroll
              for (int j = 0; j < 4; j++)
                acc[i][j] = __builtin_amdgcn_mfma_f32_16x16x32_f16(af[i], bf[j], acc[i][j], 0, 0, 0);
          }
          #pragma unroll
          for (int i = 0; i < 4; i++)
            #pragma unroll
            for (int j = 0; j < 4; j++)
              #pragma unroll
              for (int r = 0; r < 4; r++){
                int ml = wr + i*16 + kb*4 + r;
                int b = ml >> 3, tt2 = q*8 + (ml & 7);
                int n = n0 + wc + j*16 + l15;
                if (n < LMN) out[((size_t)b*TT + tt2)*LMN + n] = acc[i][j][r];
              }
        }
      }
    }
    return;
  }

  // ===================== scan WGs (bids 0..119) =====================
  {
    const f16* src = WAf + (size_t)bid*32*768;
    for (int c = tid; c < 3072; c += 256){
      int row = c/96, kc = c - row*96;
      int off = (row*1536 + kc*16) ^ ((row&7)<<4);
      *(f16x8*)(smem + off) = *(const f16x8*)(src + (size_t)row*768 + kc*8);
    }
    if (bid < 48){
      const f16* s2 = V1tf + (size_t)bid*16*3072;
      for (int c = tid; c < 6144; c += 256){
        int row = c/384, kc = c - row*384;
        int off = (row*6144 + kc*16) ^ ((row&7)<<4);
        *(f16x8*)(smem + 49152 + off) = *(const f16x8*)(s2 + (size_t)row*3072 + kc*8);
      }
    } else if (bid < 72){
      const f16* s2 = Wc1f + (size_t)(bid-48)*32*768;
      for (int c = tid; c < 3072; c += 256){
        int row = c/96, kc = c - row*96;
        int off = (row*1536 + kc*16) ^ ((row&7)<<4);
        *(f16x8*)(smem + 49152 + off) = *(const f16x8*)(s2 + (size_t)row*768 + kc*8);
      }
    } else {
      // D: 16 cf rows (u*16..) + 16 gpre rows (768+u*16..)
      int u = bid - 72;
      for (int c = tid; c < 3072; c += 256){
        int row = c/96, kc = c - row*96;
        int grow = (row < 16) ? (u*16 + row) : (768 + u*16 + (row - 16));
        int off = (row*1536 + kc*16) ^ ((row&7)<<4);
        *(f16x8*)(smem + 49152 + off) = *(const f16x8*)(WDf + (size_t)grow*768 + kc*8);
      }
    }
  }
  __syncthreads();

  const int n_a = bid*32 + (wid>>1)*16 + l15;
  float b1v = 0.f;
  if (bid < 48) b1v = b1[bid*16 + l15];
  float cpb1v = 0.f;
  if (bid >= 48 && bid < 72) cpb1v = cb1[((bid-48)*2 + (wid>>1))*16 + l15];
  float cbv = 0.f, bdgv = 0.f, gbv = 0.f; int n_d2 = 0;
  if (bid >= 72){
    n_d2 = (bid-72)*16 + l15;
    cbv = cb2[n_d2]; bdgv = bdg[n_d2]; gbv = gb_[n_d2];
  }

  for (int t = 0; t < TT; ++t){
    const int ep = t + 1;
    f32x4 cv = {0.f,0.f,0.f,0.f};
    if ((wid & 1) == 0 && n_a < 3072){
      const float* p = ctxV0T + (size_t)t*16*3072 + n_a;
      #pragma unroll
      for (int r = 0; r < 4; r++) cv[r] = p[(size_t)(kb*4+r)*3072];
    }

    if (t > 0) waitf(dfl, 48, t);
    // ==== stage A: inline LN(val,pp) -> h -> h@WA^T
    {
      const int u = wid >> 1, kh = wid & 1;
      const int k0 = kh*384 + kb*8;
      f32x4 a = {0.f,0.f,0.f,0.f};
      if (t > 0){
        const int slot = (t-1) & 3;
        float s = 0.f, ss = 0.f;
        {
          int m = lane & 15, q = lane >> 4;
          const float* pq = pp + slot*1536 + m*96 + q*24;
          #pragma unroll
          for (int j = 0; j < 12; j++){ float2 v2 = ld_actf2(pq + j*2); s += v2.x; ss += v2.y; }
        }
        s += __shfl_xor(s,16); ss += __shfl_xor(ss,16);
        s += __shfl_xor(s,32); ss += __shfl_xor(ss,32);
        float mean = s*(1.f/768.f);
        float rstd = rsqrtf(ss*(1.f/768.f) - mean*mean + 1e-5f);
        const float* vp = val + slot*12288 + (size_t)l15*768;
        const int row = u*16 + l15, rowoff = row*1536, sw = (row&7)<<4;
        #pragma unroll
        for (int b = 0; b < 12; b++){
          int kc = k0 + b*32;
          float2 e0 = ld_actf2(vp+kc), e1 = ld_actf2(vp+kc+2);
          float2 e2 = ld_actf2(vp+kc+4), e3 = ld_actf2(vp+kc+6);
          float4 g0 = *(const float4*)(og+kc), g1 = *(const float4*)(og+kc+4);
          float4 o0 = *(const float4*)(ob+kc), o1 = *(const float4*)(ob+kc+4);
          float vv[8] = {e0.x,e0.y,e1.x,e1.y,e2.x,e2.y,e3.x,e3.y};
          float gg[8] = {g0.x,g0.y,g0.z,g0.w,g1.x,g1.y,g1.z,g1.w};
          float oo[8] = {o0.x,o0.y,o0.z,o0.w,o1.x,o1.y,o1.z,o1.w};
          f16x8 va;
          #pragma unroll
          for (int j = 0; j < 8; j++){
            float y = (vv[j]-mean)*rstd*gg[j] + oo[j];
            y = fminf(5.f, fmaxf(-5.f, y));
            va[j] = (f16)y;
          }
          int wb = (rowoff + kc*2) ^ sw;
          f16x8 vb = *(const f16x8*)(smem + wb);
          a = __builtin_amdgcn_mfma_f32_16x16x32_f16(va, vb, a, 0,0,0);
        }
      }
      red_store(redbuf[wid], lane, a);
    }
    __syncthreads();
    if ((wid & 1) == 0){
      f32x4 s4 = red_sum2(redbuf, lane, wid, wid+1);
      #pragma unroll
      for (int r = 0; r < 4; r++){
        int m = kb*4 + r;
        if (n_a < 3072){
          float hv = geluf(s4[r] + cv[r]);
          st_acth(h1f + (size_t)m*3072 + n_a, hv);
        } else {
          st_actf(tfs + m*DD + (n_a - 3072), s4[r]);
        }
      }
    }
    postf(afl + bid*32, ep);
    // ==== stage B
    if (bid < 48){
      waitf(afl, 120, ep);
      const int k0 = wid*768 + kb*8;
      const f16* ap = h1f + (size_t)l15*3072 + k0;
      const int rowoff = l15*6144, sw = (l15&7)<<4;
      f32x4 a = {0.f,0.f,0.f,0.f};
      #pragma unroll
      for (int b = 0; b < 24; b++){
        int wb = (rowoff + (k0 + b*32)*2) ^ sw;
        f16x8 vb = *(const f16x8*)(smem + 49152 + wb);
        f16x8 va = ld_act16h(ap + b*32);
        a = __builtin_amdgcn_mfma_f32_16x16x32_f16(va, vb, a, 0,0,0);
      }
      red_store(redbuf[wid], lane, a);
      __syncthreads();
      if (wid == 0){
        f32x4 s4 = red_sum4(redbuf, lane);
        int n = bid*16 + l15;
        #pragma unroll
        for (int r = 0; r < 4; r++){
          int m = kb*4 + r;
          st_acth(c1f + (size_t)m*DD + n, geluf(s4[r] + b1v));
        }
      }
      postf(bfl + bid*32, ep);
    }
    // ==== stage C
    if (bid >= 48 && bid < 72){
      waitf(bfl, 48, ep);
      const int u = wid >> 1, kh = wid & 1;
      const int k0 = kh*384 + kb*8;
      const f16* ap = c1f + (size_t)l15*DD + k0;
      const int row = u*16 + l15, rowoff = row*1536, sw = (row&7)<<4;
      f32x4 a = {0.f,0.f,0.f,0.f};
      float sq = 0.f;
      #pragma unroll
      for (int b = 0; b < 12; b++){
        int wb = (rowoff + (k0 + b*32)*2) ^ sw;
        f16x8 vb = *(const f16x8*)(smem + 49152 + wb);
        f16x8 va = ld_act16h(ap + b*32);
        a = __builtin_amdgcn_mfma_f32_16x16x32_f16(va, vb, a, 0,0,0);
        #pragma unroll
        for (int j = 0; j < 8; j++){ float xv = (float)va[j]; sq = fmaf(xv, xv, sq); }
      }
      sq += __shfl_xor(sq,16); sq += __shfl_xor(sq,32);
      if (lane < 16) normp[wid][lane] = sq;
      red_store(redbuf[wid], lane, a);
      __syncthreads();
      if ((wid & 1) == 0){
        f32x4 s4 = red_sum2(redbuf, lane, wid, wid+1);
        int n = ((bid-48)*2 + (wid>>1))*16 + l15;
        #pragma unroll
        for (int r = 0; r < 4; r++){
          int m = kb*4 + r;
          float nm = normp[wid][m] + normp[wid+1][m];
          float inv = 1.f / fmaxf(sqrtf(nm), 1e-12f);
          st_acth(gcaf + (size_t)m*DD + n, geluf(s4[r]*inv + cpb1v));
        }
      }
      postf(cfl + (bid-48)*32, ep);
    }
    // ==== stage D: cf+gpre -> gate -> val + LN partials (ring slot t&3)
    if (bid >= 72){
      waitf(cfl, 24, ep);
      if (t >= 4) waitf(mfl, 16, t - 3);    // ring-4 throttle vs consumers
      const int isg = wid >> 1, kh = wid & 1;
      const int k0 = kh*384 + kb*8;
      const f16* ap = gcaf + (size_t)l15*DD + k0;
      const int row = isg*16 + l15, rowoff = row*1536, sw = (row&7)<<4;
      f32x4 a = {0.f,0.f,0.f,0.f};
      #pragma unroll
      for (int b = 0; b < 12; b++){
        int wb = (rowoff + (k0 + b*32)*2) ^ sw;
        f16x8 vb = *(const f16x8*)(smem + 49152 + wb);
        f16x8 va = ld_act16h(ap + b*32);
        a = __builtin_amdgcn_mfma_f32_16x16x32_f16(va, vb, a, 0,0,0);
      }
      red_store(redbuf[wid], lane, a);
      __syncthreads();
      if (wid == 0){
        const int u = bid - 72, slot = t & 3;
        f32x4 acf = red_sum2(redbuf, lane, 0, 1);
        f32x4 agp = red_sum2(redbuf, lane, 2, 3);
        int n = u*16 + l15;
        float valr[4];
        #pragma unroll
        for (int r = 0; r < 4; r++){
          int m = kb*4 + r;
          size_t gi_idx = ((size_t)t*16 + m)*DD + n;
          float cfv = acf[r] + cbv;
          float gpv = agp[r] + bdgv;
          float gi  = gctxT[gi_idx] + gpv + gbv;
          float gate = 1.f/(1.f + expf(-gi));
          float tf = ld_actf(tfs + m*DD + n);
          float vv = gate*(cfv + tf) + (1.f - gate)*ctxT[gi_idx];
          st_actf(val + slot*12288 + m*768 + n, vv);
          valr[r] = vv;
        }
        #pragma unroll
        for (int r = 0; r < 4; r++){
          float s2 = valr[r], ss2 = valr[r]*valr[r];
          #pragma unroll
          for (int o2 = 1; o2 < 16; o2 <<= 1){ s2 += __shfl_xor(s2, o2); ss2 += __shfl_xor(ss2, o2); }
          if (l15 == 0){
            int m = kb*4 + r;
            st_actf(pp + slot*1536 + m*96 + u*2,     s2);
            st_actf(pp + slot*1536 + m*96 + u*2 + 1, ss2);
          }
        }
      }
      postf(dfl + (bid-72)*32, ep);
    }
  }
}

// ---------------- host ----------------
extern "C" void kernel_launch(void* const* d_in, const int* in_sizes, int n_in,
                              void* d_out, int out_size, void* d_ws, size_t ws_size,
                              hipStream_t stream)
{
  (void)in_sizes; (void)n_in; (void)out_size; (void)ws_size;
  const int*   tok = (const int*)d_in[0];
  const float* emb = (const float*)d_in[1];
  const float* pos = (const float*)d_in[2];
  const float* aiw = (const float*)d_in[3];
  const float* aib = (const float*)d_in[4];
  const float* aow = (const float*)d_in[5];
  const float* aob = (const float*)d_in[6];
  const float* fw1 = (const float*)d_in[7];
  const float* fb1 = (const float*)d_in[8];
  const float* fw2 = (const float*)d_in[9];
  const float* fb2 = (const float*)d_in[10];
  const float* n1g = (const float*)d_in[11];
  const float* n1b = (const float*)d_in[12];
  const float* n2g = (const float*)d_in[13];
  const float* n2b = (const float*)d_in[14];
  const float* eng = (const float*)d_in[15];
  const float* enb = (const float*)d_in[16];
  const float* V0  = (const float*)d_in[17];
  const float* b0  = (const float*)d_in[18];
  const float* V1  = (const float*)d_in[19];
  const float* b1  = (const float*)d_in[20];
  const float* cw1 = (const float*)d_in[21];
  const float* cb1 = (const float*)d_in[22];
  const float* cw2 = (const float*)d_in[23];
  const float* cb2 = (const float*)d_in[24];
  const float* gw  = (const float*)d_in[25];
  const float* gb  = (const float*)d_in[26];
  const float* tw  = (const float*)d_in[27];
  const float* Rm  = (const float*)d_in[28];
  const float* og  = (const float*)d_in[29];
  const float* ob  = (const float*)d_in[30];
  const float* lmw = (const float*)d_in[31];
  float* out = (float*)d_out;

  char* base = (char*)d_ws; size_t off = 0;
  auto alloc = [&](size_t bytes)->void*{
    off = (off + 255) & ~(size_t)255; void* p = base + off; off += bytes; return p; };

  float* x     = (float*)alloc((size_t)MR*DD*4);
  float* xn    = (float*)alloc((size_t)MR*DD*4);
  float* qkv   = (float*)alloc((size_t)MR*2304*4);
  float* o_    = (float*)alloc((size_t)MR*DD*4);
  float* mid   = (float*)alloc((size_t)MR*2048*4);
  float* ctx   = (float*)alloc((size_t)MR*DD*4);
  float* ctxT  = (float*)alloc((size_t)MR*DD*4);
  float* V0t   = (float*)alloc((size_t)3072*768*4);
  float* cw2t  = (float*)alloc((size_t)768*768*4);
  float* ctxV0T= (float*)alloc((size_t)MR*3072*4);
  float* gctxT = (float*)alloc((size_t)MR*DD*4);
  float* bdg   = (float*)alloc(768*4);
  f16*   WAf   = (f16*)alloc((size_t)3840*768*2);
  f16*   V1tf  = (f16*)alloc((size_t)768*3072*2);
  f16*   Wc1f  = (f16*)alloc((size_t)768*768*2);
  f16*   WDf   = (f16*)alloc((size_t)1536*768*2);
  f16*   lmw16 = (f16*)alloc((size_t)LMN*768*2);
  f16*   hf    = (f16*)alloc((size_t)MR*DD*2);
  f16*   h1f   = (f16*)alloc((size_t)16*3072*2);
  f16*   c1f   = (f16*)alloc((size_t)16*768*2);
  f16*   gcaf  = (f16*)alloc((size_t)16*768*2);
  float* val   = (float*)alloc((size_t)4*16*768*4);
  float* pp    = (float*)alloc((size_t)4*16*96*4);
  float* tfs   = (float*)alloc((size_t)16*768*4);
  int*   flags = (int*)alloc((size_t)512*32*4);

  k_init<<<1, 256, 0, stream>>>(flags);
  k_all<<<GRID, 256, 0, stream>>>(tok, emb, pos, aiw, aib, aow, aob,
      fw1, fb1, fw2, fb2, n1g, n1b, n2g, n2b, eng, enb,
      V0, b0, V1, b1, cw1, cb1, cw2, cb2, gw, gb, tw, Rm, og, ob, lmw,
      x, xn, qkv, o_, mid, ctx, ctxT, V0t, cw2t, ctxV0T, gctxT, bdg,
      WAf, V1tf, Wc1f, WDf, lmw16, hf, h1f, c1f, gcaf, val, pp, tfs, flags, out);
}

// Round 15
// 2599.932 us; speedup vs baseline: 1.1994x; 1.1994x over previous
//
#include <hip/hip_runtime.h>
#include <math.h>

typedef _Float16 f16;
typedef f16 f16x8 __attribute__((ext_vector_type(8)));
typedef f16 f16x4 __attribute__((ext_vector_type(4)));
typedef float f32x4 __attribute__((ext_vector_type(4)));
typedef unsigned int u32;
typedef unsigned long long u64;

#define TT 64
#define DD 768
#define MR 1024
#define ALPHAF 0.4f
#define NWG 120
#define GRID 240
#define LMN 50257
#define LMK 768

__device__ __forceinline__ float geluf(float x){
  return 0.5f*x*(1.0f + erff(x*0.70710678118654752f));
}

// ---- coherent (agent-scope, LLC) accessors ----
__device__ __forceinline__ u64 ld_a64(const void* p){
  return __hip_atomic_load((const u64*)p, __ATOMIC_RELAXED, __HIP_MEMORY_SCOPE_AGENT);
}
__device__ __forceinline__ f16x8 ld_act16h(const f16* p){
  union { u64 u[2]; f16x8 v; } c;
  c.u[0] = ld_a64(p); c.u[1] = ld_a64(p + 4); return c.v;
}
__device__ __forceinline__ float ld_actf(const float* p){
  union { u32 u; float f; } c;
  c.u = __hip_atomic_load((const u32*)p, __ATOMIC_RELAXED, __HIP_MEMORY_SCOPE_AGENT);
  return c.f;
}
__device__ __forceinline__ void st_actf(float* p, float v){
  union { u32 u; float f; } c; c.f = v;
  __hip_atomic_store((u32*)p, c.u, __ATOMIC_RELAXED, __HIP_MEMORY_SCOPE_AGENT);
}
__device__ __forceinline__ void st_acth(f16* p, float v){
  union { unsigned short u; f16 h; } c; c.h = (f16)v;
  __hip_atomic_store((unsigned short*)p, c.u, __ATOMIC_RELAXED, __HIP_MEMORY_SCOPE_AGENT);
}

// ---- encoder phase barrier ----
__device__ __forceinline__ void egbar(int* ef, int ep){
  __syncthreads();
  if (threadIdx.x == 0){
    __threadfence();
    __hip_atomic_store(ef + blockIdx.x*32, ep, __ATOMIC_RELAXED, __HIP_MEMORY_SCOPE_AGENT);
  }
  {
    int id = threadIdx.x; bool active = id < GRID;
    const int* fp = ef + id*32;
    while (true){
      int v = active ? __hip_atomic_load(fp, __ATOMIC_RELAXED, __HIP_MEMORY_SCOPE_AGENT) : ep;
      if (__ballot(v >= ep) == ~0ull) break;
      __builtin_amdgcn_s_sleep(1);
    }
  }
  __syncthreads();
  if (threadIdx.x == 0) __threadfence();
  __syncthreads();
}

// ---- scan flag primitives ----
__device__ __forceinline__ void postf(int* f, int ep){
  asm volatile("s_waitcnt vmcnt(0)" ::: "memory");
  __syncthreads();
  if (threadIdx.x == 0)
    __hip_atomic_store(f, ep, __ATOMIC_RELAXED, __HIP_MEMORY_SCOPE_AGENT);
}
__device__ __forceinline__ void waitf(const int* f, int n, int ep){
  if (threadIdx.x < 64){
    int lane = threadIdx.x;
    while (true){
      bool ok = true;
      for (int i = lane; i < n; i += 64){
        if (__hip_atomic_load(f + i*32, __ATOMIC_RELAXED, __HIP_MEMORY_SCOPE_AGENT) < ep){
          ok = false; break;
        }
      }
      if (__ballot(ok) == ~0ull) break;
      __builtin_amdgcn_s_sleep(1);
    }
  }
  __syncthreads();
}

__device__ __forceinline__ void red_store(float* rb, int lane, f32x4 a){
  rb[lane] = a[0]; rb[64+lane] = a[1]; rb[128+lane] = a[2]; rb[192+lane] = a[3];
}
__device__ __forceinline__ f32x4 red_sum4(float rb[4][256], int lane){
  f32x4 s;
  #pragma unroll
  for (int r = 0; r < 4; r++)
    s[r] = rb[0][r*64+lane] + rb[1][r*64+lane] + rb[2][r*64+lane] + rb[3][r*64+lane];
  return s;
}
__device__ __forceinline__ f32x4 red_sum2(float rb[4][256], int lane, int w0, int w1){
  f32x4 s;
  #pragma unroll
  for (int r = 0; r < 4; r++)
    s[r] = rb[w0][r*64+lane] + rb[w1][r*64+lane];
  return s;
}

// ---- per-row LN stats (mean, rstd) ----
__device__ void dev_rowstats(const float* xr, float* red, float2* outstat){
  int tid = threadIdx.x, lane = tid & 63, wid = tid >> 6;
  float s = 0.f, ss = 0.f;
  #pragma unroll
  for (int j = 0; j < 3; j++){ float t0 = xr[tid + j*256]; s += t0; ss += t0*t0; }
  #pragma unroll
  for (int o = 1; o < 64; o <<= 1){ s += __shfl_xor(s, o); ss += __shfl_xor(ss, o); }
  if (lane == 0){ red[wid] = s; red[4+wid] = ss; }
  __syncthreads();
  s  = red[0]+red[1]+red[2]+red[3];
  ss = red[4]+red[5]+red[6]+red[7];
  float mean = s*(1.f/768.f);
  float rstd = rsqrtf(ss*(1.f/768.f) - mean*mean + 1e-5f);
  if (tid == 0){ outstat->x = mean; outstat->y = rstd; }
  __syncthreads();
}

// ---- ff2 finish: x += bias + sum(partials); then stats or final LN+l2norm ----
__device__ void dev_ff2_finish(const float* pfb, const float* bias, float* x, int m,
    float* red, float2* outstat, bool finalln,
    const float* g, const float* b, float* ctx, float* ctxT){
  int tid = threadIdx.x, lane = tid & 63, wid = tid >> 6;
  float* xr = x + (size_t)m*DD;
  float v[3]; float s = 0.f, ss = 0.f;
  #pragma unroll
  for (int j = 0; j < 3; j++){
    int n = tid + j*256;
    size_t o = (size_t)m*DD + n;
    float t0 = xr[n] + bias[n] + pfb[o] + pfb[(size_t)MR*DD + o]
             + pfb[2*(size_t)MR*DD + o] + pfb[3*(size_t)MR*DD + o];
    xr[n] = t0; v[j] = t0; s += t0; ss += t0*t0;
  }
  #pragma unroll
  for (int o = 1; o < 64; o <<= 1){ s += __shfl_xor(s, o); ss += __shfl_xor(ss, o); }
  if (lane == 0){ red[wid] = s; red[4+wid] = ss; }
  __syncthreads();
  s  = red[0]+red[1]+red[2]+red[3];
  ss = red[4]+red[5]+red[6]+red[7];
  float mean = s*(1.f/768.f);
  float rstd = rsqrtf(ss*(1.f/768.f) - mean*mean + 1e-5f);
  if (!finalln){
    if (tid == 0){ outstat->x = mean; outstat->y = rstd; }
    __syncthreads();
    return;
  }
  float y[3];
  #pragma unroll
  for (int j = 0; j < 3; j++){ int n = tid + j*256; y[j] = (v[j]-mean)*rstd*g[n] + b[n]; }
  float n2 = y[0]*y[0] + y[1]*y[1] + y[2]*y[2];
  #pragma unroll
  for (int o = 1; o < 64; o <<= 1) n2 += __shfl_xor(n2, o);
  __syncthreads();
  if (lane == 0) red[wid] = n2;
  __syncthreads();
  n2 = red[0]+red[1]+red[2]+red[3];
  float inv = 1.f / fmaxf(sqrtf(n2), 1e-12f);
  float* cT = ctxT + ((size_t)(m & 63)*16 + (m >> 6))*DD;
  #pragma unroll
  for (int j = 0; j < 3; j++){
    int n = tid + j*256;
    float yy = y[j]*inv;
    ctx[(size_t)m*DD + n] = yy;
    cT[n] = yy;
  }
  __syncthreads();
}

// 128x128 GEMM tile, software-pipelined, optional fused-LN on A
__device__ void dev_gemm_tile(char* lds, const float* A, int lda,
    const float* Bw, int ldb, int nrb, int N, int K, int m0, int n0,
    const float* bias, const float* res, float* outF, f16* outH,
    float scale, int act, int operm,
    const float2* lnstats, const float* lng, const float* lnb)
{
  int tid = threadIdx.x;
  int lane = tid & 63, wid = tid >> 6;
  int wr = (wid >> 1)*64, wc = (wid & 1)*64;
  int l15 = lane & 15, kb = lane >> 4;
  f32x4 acc[4][4];
  #pragma unroll
  for (int i = 0; i < 4; i++)
    #pragma unroll
    for (int j = 0; j < 4; j++){ f32x4 z = {0.f,0.f,0.f,0.f}; acc[i][j] = z; }
  int rA = tid >> 3;
  int k4 = (tid & 7)*4;
  float2 msr[4];
  if (lnstats){
    #pragma unroll
    for (int it = 0; it < 4; ++it) msr[it] = lnstats[m0 + it*32 + rA];
  }
  float4 va[4], vb[4];
  float4 g4, b4;
  if (lnstats){ g4 = *(const float4*)(lng + k4); b4 = *(const float4*)(lnb + k4); }
  #pragma unroll
  for (int it = 0; it < 4; ++it){
    int r = it*32 + rA;
    va[it] = *(const float4*)(A + (size_t)(m0+r)*lda + k4);
    int rB = n0 + r;
    if (rB < nrb) vb[it] = *(const float4*)(Bw + (size_t)rB*ldb + k4);
    else { vb[it].x=0.f; vb[it].y=0.f; vb[it].z=0.f; vb[it].w=0.f; }
  }
  if (lnstats){
    #pragma unroll
    for (int it = 0; it < 4; ++it){
      float mn = msr[it].x, rs = msr[it].y;
      va[it].x = (va[it].x-mn)*rs*g4.x + b4.x;
      va[it].y = (va[it].y-mn)*rs*g4.y + b4.y;
      va[it].z = (va[it].z-mn)*rs*g4.z + b4.z;
      va[it].w = (va[it].w-mn)*rs*g4.w + b4.w;
    }
  }
  for (int kk = 0; kk < K; kk += 32){
    char* cb = lds + (((kk >> 5) & 1) ? 20480 : 0);
    f16 (*As)[40] = (f16(*)[40])cb;
    f16 (*Bs)[40] = (f16(*)[40])(cb + 10240);
    #pragma unroll
    for (int it = 0; it < 4; ++it){
      int r = it*32 + rA;
      *(f16x4*)(&As[r][k4]) = (f16x4){(f16)va[it].x,(f16)va[it].y,(f16)va[it].z,(f16)va[it].w};
      *(f16x4*)(&Bs[r][k4]) = (f16x4){(f16)vb[it].x,(f16)vb[it].y,(f16)vb[it].z,(f16)vb[it].w};
    }
    __syncthreads();
    if (kk + 32 < K){
      if (lnstats){ g4 = *(const float4*)(lng + kk + 32 + k4); b4 = *(const float4*)(lnb + kk + 32 + k4); }
      #pragma unroll
      for (int it = 0; it < 4; ++it){
        int r = it*32 + rA;
        va[it] = *(const float4*)(A + (size_t)(m0+r)*lda + kk + 32 + k4);
        int rB = n0 + r;
        if (rB < nrb) vb[it] = *(const float4*)(Bw + (size_t)rB*ldb + kk + 32 + k4);
        else { vb[it].x=0.f; vb[it].y=0.f; vb[it].z=0.f; vb[it].w=0.f; }
      }
      if (lnstats){
        #pragma unroll
        for (int it = 0; it < 4; ++it){
          float mn = msr[it].x, rs = msr[it].y;
          va[it].x = (va[it].x-mn)*rs*g4.x + b4.x;
          va[it].y = (va[it].y-mn)*rs*g4.y + b4.y;
          va[it].z = (va[it].z-mn)*rs*g4.z + b4.z;
          va[it].w = (va[it].w-mn)*rs*g4.w + b4.w;
        }
      }
    }
    f16x8 af[4], bfv[4];
    #pragma unroll
    for (int i = 0; i < 4; i++) af[i]  = *(const f16x8*)(&As[wr + i*16 + l15][kb*8]);
    #pragma unroll
    for (int j = 0; j < 4; j++) bfv[j] = *(const f16x8*)(&Bs[wc + j*16 + l15][kb*8]);
    #pragma unroll
    for (int i = 0; i < 4; i++)
      #pragma unroll
      for (int j = 0; j < 4; j++)
        acc[i][j] = __builtin_amdgcn_mfma_f32_16x16x32_f16(af[i], bfv[j], acc[i][j], 0, 0, 0);
  }
  __syncthreads();
  #pragma unroll
  for (int i = 0; i < 4; i++){
    #pragma unroll
    for (int j = 0; j < 4; j++){
      #pragma unroll
      for (int r = 0; r < 4; r++){
        int m = m0 + wr + i*16 + kb*4 + r;
        int n = n0 + wc + j*16 + l15;
        if (n < N){
          float v = acc[i][j][r]*scale;
          if (bias) v += bias[n];
          if (act == 1) v = geluf(v);
          if (res) v += res[(size_t)m*N + n];
          size_t off;
          if (operm == 0) off = (size_t)m*N + n;
          else            off = ((size_t)(m & 63)*16 + (m >> 6))*N + n;
          if (outF) outF[off] = v;
          if (outH) outH[off] = (f16)v;
        }
      }
    }
  }
}

__device__ void dev_attn(char* lds, const float* qkv, float* o, int bh){
  float (*kv)[96] = (float(*)[96])lds;
  float (*sm)[68] = (float(*)[68])(lds + 24576);
  int b = bh >> 3, h = bh & 7;
  int tid = threadIdx.x;
  const float* base = qkv + (size_t)b*64*2304 + h*96;
  for (int idx = tid; idx < 64*96; idx += 256){ int i = idx/96, d = idx - i*96;
    kv[i][d] = base[(size_t)i*2304 + 768 + d]; }
  __syncthreads();
  {
    int i = tid >> 2;
    const float* q = base + (size_t)i*2304;
    int j0 = (tid & 3)*16;
    for (int jj = 0; jj < 16; jj++){
      int j = j0 + jj;
      float sv = -1e30f;
      if (j <= i){ float acc = 0.f;
        for (int d = 0; d < 96; d++) acc += q[d]*kv[j][d];
        sv = acc*0.10206207261596576f; }
      sm[i][j] = sv;
    }
  }
  __syncthreads();
  for (int idx = tid; idx < 64*96; idx += 256){ int i = idx/96, d = idx - i*96;
    kv[i][d] = base[(size_t)i*2304 + 1536 + d]; }
  if (tid < 64){
    int i = tid;
    float mx = -1e30f;
    for (int j = 0; j <= i; j++) mx = fmaxf(mx, sm[i][j]);
    float sum = 0.f;
    for (int j = 0; j <= i; j++){ float e = expf(sm[i][j]-mx); sm[i][j] = e; sum += e; }
    float inv = 1.f/sum;
    for (int j = 0; j <= i; j++) sm[i][j] *= inv;
  }
  __syncthreads();
  for (int idx = tid; idx < 64*96; idx += 256){
    int i = idx/96, d = idx - i*96;
    float acc = 0.f;
    for (int j = 0; j <= i; j++) acc += sm[i][j]*kv[j][d];
    o[(size_t)(b*64+i)*768 + h*96 + d] = acc;
  }
  __syncthreads();
}

__device__ void dev_tr_f(char* lds, const float* in, float* out, int R, int C, int bx, int by){
  float (*tile)[33] = (float(*)[33])lds;
  int r0 = by*32, c0 = bx*32;
  int tx = threadIdx.x & 31, ty = threadIdx.x >> 5;
  #pragma unroll
  for (int i = 0; i < 32; i += 8) tile[ty+i][tx] = in[(size_t)(r0+ty+i)*C + (c0+tx)];
  __syncthreads();
  #pragma unroll
  for (int i = 0; i < 32; i += 8) out[(size_t)(c0+ty+i)*R + (r0+tx)] = tile[tx][ty+i];
  __syncthreads();
}
__device__ void dev_tr_h(char* lds, const float* in, f16* out, int R, int C, int bx, int by){
  float (*tile)[33] = (float(*)[33])lds;
  int r0 = by*32, c0 = bx*32;
  int tx = threadIdx.x & 31, ty = threadIdx.x >> 5;
  #pragma unroll
  for (int i = 0; i < 32; i += 8) tile[ty+i][tx] = in[(size_t)(r0+ty+i)*C + (c0+tx)];
  __syncthreads();
  #pragma unroll
  for (int i = 0; i < 32; i += 8) out[(size_t)(c0+ty+i)*R + (r0+tx)] = (f16)tile[tx][ty+i];
  __syncthreads();
}

__global__ void k_init(int* flags){
  for (int i = threadIdx.x; i < 512*32; i += 256) flags[i] = 0;
}

// =================== MEGA KERNEL ===================
__global__ __launch_bounds__(256, 1) void k_all(
  const int* tok, const float* emb, const float* pos,
  const float* aiw, const float* aib, const float* aow, const float* aob,
  const float* fw1, const float* fb1, const float* fw2, const float* fb2,
  const float* n1g, const float* n1b, const float* n2g, const float* n2b,
  const float* eng, const float* enb,
  const float* V0, const float* b0, const float* V1, const float* b1,
  const float* cw1, const float* cb1, const float* cw2, const float* cb2,
  const float* gw, const float* gb_, const float* tw, const float* Rm,
  const float* og, const float* ob, const float* lmw,
  float* x, float* qkv, float* o_, float* mid,
  float* ctx, float* ctxT, float* V0t, float* cw2t,
  float* ctxV0T, float* gctxT, float* bdg,
  float2* stats, float* pfb,
  f16* WAf, f16* V1tf, f16* Wc1f, f16* WDf, f16* lmw16,
  f16* hf, f16* h1f, f16* c1f, f16* gcaf,
  float* cf, float* gpre, float* tfs, int* flags, float* out)
{
  __shared__ __align__(16) char smem[147456];
  __shared__ float redbuf[4][256];
  __shared__ float normp[4][16];
  __shared__ float red[8];
  const int tid = threadIdx.x, lane = tid & 63, wid = tid >> 6;
  const int bid = blockIdx.x;
  const int l15 = lane & 15, kb = lane >> 4;
  int* afl = flags;
  int* bfl = flags + 120*32;
  int* cfl = flags + 168*32;
  int* dfl = flags + 192*32;
  int* mfl = flags + 240*32;
  int* encf = flags + 256*32;
  int eep = 0;

  // ===== P0: embed + LN1(l=0) stats =====
  for (int m = bid; m < MR; m += GRID){
    int t = m & 63; int id = tok[m];
    const float* e = emb + (size_t)id*DD;
    const float* p = pos + (size_t)t*DD;
    float* xr = x + (size_t)m*DD;
    float s = 0.f, ss = 0.f;
    #pragma unroll
    for (int j = 0; j < 3; j++){
      int n = tid + j*256;
      float t0 = e[n] + p[n];
      xr[n] = t0; s += t0; ss += t0*t0;
    }
    #pragma unroll
    for (int o2 = 1; o2 < 64; o2 <<= 1){ s += __shfl_xor(s, o2); ss += __shfl_xor(ss, o2); }
    if (lane == 0){ red[wid] = s; red[4+wid] = ss; }
    __syncthreads();
    s  = red[0]+red[1]+red[2]+red[3];
    ss = red[4]+red[5]+red[6]+red[7];
    float mean = s*(1.f/768.f);
    float rstd = rsqrtf(ss*(1.f/768.f) - mean*mean + 1e-5f);
    if (tid == 0){ stats[m].x = mean; stats[m].y = rstd; }
    __syncthreads();
  }
  egbar(encf, ++eep);

  // ===== encoder layers =====
  for (int l = 0; l < 2; l++){
    // qkv GEMM with fused LN1
    for (int tl = bid; tl < 144; tl += GRID)
      dev_gemm_tile(smem, x, 768, aiw + (size_t)l*2304*768, 768, 2304, 2304, 768,
                    (tl % 8)*128, (tl / 8)*128, aib + l*2304, nullptr, qkv, nullptr, 1.f, 0, 0,
                    stats, n1g + l*DD, n1b + l*DD);
    egbar(encf, ++eep);
    for (int u = bid; u < 128; u += GRID) dev_attn(smem, qkv, o_, u);
    egbar(encf, ++eep);
    for (int tl = bid; tl < 48; tl += GRID)
      dev_gemm_tile(smem, o_, 768, aow + (size_t)l*768*768, 768, 768, 768, 768,
                    (tl % 8)*128, (tl / 8)*128, aob + l*768, x, x, nullptr, 1.f, 0, 0,
                    nullptr, nullptr, nullptr);
    egbar(encf, ++eep);
    // LN2 stats
    for (int m = bid; m < MR; m += GRID) dev_rowstats(x + (size_t)m*DD, red, stats + m);
    egbar(encf, ++eep);
    // ff1 with fused LN2 (gelu out)
    for (int tl = bid; tl < 128; tl += GRID)
      dev_gemm_tile(smem, x, 768, fw1 + (size_t)l*2048*768, 768, 2048, 2048, 768,
                    (tl % 8)*128, (tl / 8)*128, fb1 + l*2048, nullptr, mid, nullptr, 1.f, 1, 0,
                    stats, n2g + l*DD, n2b + l*DD);
    egbar(encf, ++eep);
    // ff2 split-K x4 -> partials
    for (int t2 = bid; t2 < 192; t2 += GRID){
      int tl = t2 >> 2, ks = t2 & 3;
      dev_gemm_tile(smem, mid + ks*512, 2048, fw2 + (size_t)l*768*2048 + ks*512, 2048, 768, 768, 512,
                    (tl % 8)*128, (tl / 8)*128, nullptr, nullptr,
                    pfb + (size_t)ks*MR*DD, nullptr, 1.f, 0, 0,
                    nullptr, nullptr, nullptr);
    }
    egbar(encf, ++eep);
    // finish: x += fb2 + sum(partials); stats for next LN1, or final LN+l2norm
    for (int m = bid; m < MR; m += GRID)
      dev_ff2_finish(pfb, fb2 + l*DD, x, m, red, stats + m, (l == 1), eng, enb, ctx, ctxT);
    egbar(encf, ++eep);
  }

  // ===== P17: transposes + small casts + bdg =====
  for (int task = bid; task < 5184; task += GRID){
    if (task < 2304)      dev_tr_f(smem, V0, V0t, 768, 3072, task % 96, task / 96);
    else if (task < 2880){ int t2 = task - 2304; dev_tr_f(smem, cw2, cw2t, 768, 768, t2 % 24, t2 / 24); }
    else                 { int t2 = task - 2880; dev_tr_h(smem, V1, V1tf, 3072, 768, t2 % 24, t2 / 24); }
  }
  {
    const int g0 = bid*256 + tid, stride = GRID*256;
    for (int i = g0; i < 73728; i += stride){
      float4 a = ((const float4*)cw1)[i*2]; float4 b2 = ((const float4*)cw1)[i*2+1];
      ((f16x8*)Wc1f)[i] = (f16x8){(f16)a.x,(f16)a.y,(f16)a.z,(f16)a.w,(f16)b2.x,(f16)b2.y,(f16)b2.z,(f16)b2.w};
    }
    for (int i = g0; i < 73728; i += stride){
      float4 a = ((const float4*)cw2)[i*2]; float4 b2 = ((const float4*)cw2)[i*2+1];
      ((f16x8*)WDf)[i] = (f16x8){(f16)a.x,(f16)a.y,(f16)a.z,(f16)a.w,(f16)b2.x,(f16)b2.y,(f16)b2.z,(f16)b2.w};
    }
    for (int g = g0; g < 768; g += stride){
      const float* row = gw + (size_t)g*1536 + 768;
      float s = 0.f;
      for (int j = 0; j < 768; j++) s += cb2[j]*row[j];
      bdg[g] = s;
    }
  }
  egbar(encf, ++eep);

  // ===== P18: precompute GEMMs =====
  for (int task = bid; task < 456; task += GRID){
    if (task < 144)
      dev_gemm_tile(smem, V0t, 768, Rm, 768, 768, 768, 768,
                    (task % 24)*128, (task / 24)*128, nullptr, nullptr, nullptr, WAf, ALPHAF, 0, 0,
                    nullptr, nullptr, nullptr);
    else if (task < 180){ int t2 = task - 144;
      dev_gemm_tile(smem, tw, 768, Rm, 768, 768, 768, 768,
                    (t2 % 6)*128, (t2 / 6)*128, nullptr, nullptr, nullptr, WAf + (size_t)3072*768, ALPHAF, 0, 0,
                    nullptr, nullptr, nullptr); }
    else if (task < 372){ int t2 = task - 180;
      dev_gemm_tile(smem, ctx, 768, V0t, 768, 3072, 3072, 768,
                    (t2 % 8)*128, (t2 / 8)*128, b0, nullptr, ctxV0T, nullptr, 1.f, 0, 1,
                    nullptr, nullptr, nullptr); }
    else if (task < 420){ int t2 = task - 372;
      dev_gemm_tile(smem, ctx, 768, gw, 1536, 768, 768, 768,
                    (t2 % 8)*128, (t2 / 8)*128, nullptr, nullptr, gctxT, nullptr, 1.f, 0, 1,
                    nullptr, nullptr, nullptr); }
    else { int t2 = task - 420;
      dev_gemm_tile(smem, gw + 768, 1536, cw2t, 768, 768, 768, 768,
                    (t2 % 6)*128, (t2 / 6)*128, nullptr, nullptr, nullptr, WDf + (size_t)768*768, 1.f, 0, 0,
                    nullptr, nullptr, nullptr); }
  }
  egbar(encf, ++eep);

  // ===================== lm-head consumers =====================
  if (bid >= NWG){
    const int lw = bid - NWG;
    const int wr = (wid >> 1)*64, wc = (wid & 1)*64;
    for (int nt = lw; nt < 393; nt += 120){
      int r0 = nt*128;
      int rend = r0 + 128; if (rend > LMN) rend = LMN;
      int u0 = r0*96, u1 = rend*96;
      for (int i = u0 + tid; i < u1; i += 256){
        float4 a = ((const float4*)lmw)[(size_t)i*2];
        float4 b2 = ((const float4*)lmw)[(size_t)i*2+1];
        ((f16x8*)lmw16)[i] = (f16x8){(f16)a.x,(f16)a.y,(f16)a.z,(f16)a.w,
                                     (f16)b2.x,(f16)b2.y,(f16)b2.z,(f16)b2.w};
      }
    }
    __syncthreads();
    for (int q = 0; q < 8; ++q){
      waitf(mfl, 16, q*8 + 8);
      size_t arow[4];
      #pragma unroll
      for (int i = 0; i < 4; i++){
        int rl = wr + i*16 + l15;
        arow[i] = ((size_t)(rl >> 3)*TT + q*8 + (rl & 7))*DD + kb*8;
      }
      for (int nt = lw; nt < 393; nt += 120){
        int n0 = nt*128;
        size_t brow[4];
        #pragma unroll
        for (int j = 0; j < 4; j++){
          int n = n0 + wc + j*16 + l15;
          if (n > LMN-1) n = LMN-1;
          brow[j] = (size_t)n*LMK + kb*8;
        }
        f32x4 acc[4][4];
        #pragma unroll
        for (int i = 0; i < 4; i++)
          #pragma unroll
          for (int j = 0; j < 4; j++){ f32x4 z = {0.f,0.f,0.f,0.f}; acc[i][j] = z; }
        #pragma unroll 4
        for (int kk = 0; kk < LMK; kk += 32){
          f16x8 af[4], bf[4];
          #pragma unroll
          for (int i = 0; i < 4; i++) af[i] = ld_act16h(hf + arow[i] + kk);
          #pragma unroll
          for (int j = 0; j < 4; j++) bf[j] = *(const f16x8*)(lmw16 + brow[j] + kk);
          #pragma unroll
          for (int i = 0; i < 4; i++)
            #pragma unroll
            for (int j = 0; j < 4; j++)
              acc[i][j] = __builtin_amdgcn_mfma_f32_16x16x32_f16(af[i], bf[j], acc[i][j], 0, 0, 0);
        }
        #pragma unroll
        for (int i = 0; i < 4; i++)
          #pragma unroll
          for (int j = 0; j < 4; j++)
            #pragma unroll
            for (int r = 0; r < 4; r++){
              int ml = wr + i*16 + kb*4 + r;
              int b = ml >> 3, tt2 = q*8 + (ml & 7);
              int n = n0 + wc + j*16 + l15;
              if (n < LMN) out[((size_t)b*TT + tt2)*LMN + n] = acc[i][j][r];
            }
      }
    }
    return;
  }

  // ===================== scan WGs (bids 0..119) =====================
  {
    const f16* src = WAf + (size_t)bid*32*768;
    for (int c = tid; c < 3072; c += 256){
      int row = c/96, kc = c - row*96;
      int off = (row*1536 + kc*16) ^ ((row&7)<<4);
      *(f16x8*)(smem + off) = *(const f16x8*)(src + (size_t)row*768 + kc*8);
    }
    if (bid < 48){
      const f16* s2 = V1tf + (size_t)bid*16*3072;
      for (int c = tid; c < 6144; c += 256){
        int row = c/384, kc = c - row*384;
        int off = (row*6144 + kc*16) ^ ((row&7)<<4);
        *(f16x8*)(smem + 49152 + off) = *(const f16x8*)(s2 + (size_t)row*3072 + kc*8);
      }
    } else if (bid < 72){
      const f16* s2 = Wc1f + (size_t)(bid-48)*32*768;
      for (int c = tid; c < 3072; c += 256){
        int row = c/96, kc = c - row*96;
        int off = (row*1536 + kc*16) ^ ((row&7)<<4);
        *(f16x8*)(smem + 49152 + off) = *(const f16x8*)(s2 + (size_t)row*768 + kc*8);
      }
    } else {
      const f16* s2 = WDf + (size_t)(bid-72)*32*768;
      for (int c = tid; c < 3072; c += 256){
        int row = c/96, kc = c - row*96;
        int off = (row*1536 + kc*16) ^ ((row&7)<<4);
        *(f16x8*)(smem + 49152 + off) = *(const f16x8*)(s2 + (size_t)row*768 + kc*8);
      }
    }
  }
  __syncthreads();

  const int n_a = bid*32 + (wid>>1)*16 + l15;
  float b1v = 0.f;
  if (bid < 48) b1v = b1[bid*16 + l15];
  float cpb1v = 0.f;
  if (bid >= 48 && bid < 72) cpb1v = cb1[((bid-48)*2 + (wid>>1))*16 + l15];
  float dbv = 0.f; int n_d = 0;
  if (bid >= 72){
    n_d = ((bid-72)*2 + (wid>>1))*16 + l15;
    dbv = (n_d < 768) ? cb2[n_d] : bdg[n_d - 768];
  }
  float gb3[3], og3[3], ob3[3];
  if (bid < 16){
    #pragma unroll
    for (int j = 0; j < 3; j++){
      int n = tid + j*256;
      gb3[j] = gb_[n]; og3[j] = og[n]; ob3[j] = ob[n];
    }
  }

  for (int t = 0; t < TT; ++t){
    const int ep = t + 1;
    f32x4 cv = {0.f,0.f,0.f,0.f};
    if ((wid & 1) == 0 && n_a < 3072){
      const float* p = ctxV0T + (size_t)t*16*3072 + n_a;
      #pragma unroll
      for (int r = 0; r < 4; r++) cv[r] = p[(size_t)(kb*4+r)*3072];
    }

    if (t > 0) waitf(mfl, 16, t);
    // ==== stage A
    {
      const int u = wid >> 1, kh = wid & 1;
      const int k0 = kh*384 + kb*8;
      f32x4 a = {0.f,0.f,0.f,0.f};
      if (t > 0){
        const f16* ap = hf + ((size_t)l15*TT + (t-1))*DD + k0;
        const int row = u*16 + l15, rowoff = row*1536, sw = (row&7)<<4;
        #pragma unroll
        for (int b = 0; b < 12; b++){
          int wb = (rowoff + (k0 + b*32)*2) ^ sw;
          f16x8 vb = *(const f16x8*)(smem + wb);
          f16x8 va = ld_act16h(ap + b*32);
          a = __builtin_amdgcn_mfma_f32_16x16x32_f16(va, vb, a, 0,0,0);
        }
      }
      red_store(redbuf[wid], lane, a);
    }
    __syncthreads();
    if ((wid & 1) == 0){
      f32x4 s4 = red_sum2(redbuf, lane, wid, wid+1);
      #pragma unroll
      for (int r = 0; r < 4; r++){
        int m = kb*4 + r;
        if (n_a < 3072){
          float hv = geluf(s4[r] + cv[r]);
          st_acth(h1f + (size_t)m*3072 + n_a, hv);
        } else {
          st_actf(tfs + m*DD + (n_a - 3072), s4[r]);
        }
      }
    }
    postf(afl + bid*32, ep);
    // ==== stage B
    if (bid < 48){
      waitf(afl, 120, ep);
      const int k0 = wid*768 + kb*8;
      const f16* ap = h1f + (size_t)l15*3072 + k0;
      const int rowoff = l15*6144, sw = (l15&7)<<4;
      f32x4 a = {0.f,0.f,0.f,0.f};
      #pragma unroll
      for (int b = 0; b < 24; b++){
        int wb = (rowoff + (k0 + b*32)*2) ^ sw;
        f16x8 vb = *(const f16x8*)(smem + 49152 + wb);
        f16x8 va = ld_act16h(ap + b*32);
        a = __builtin_amdgcn_mfma_f32_16x16x32_f16(va, vb, a, 0,0,0);
      }
      red_store(redbuf[wid], lane, a);
      __syncthreads();
      if (wid == 0){
        f32x4 s4 = red_sum4(redbuf, lane);
        int n = bid*16 + l15;
        #pragma unroll
        for (int r = 0; r < 4; r++){
          int m = kb*4 + r;
          st_acth(c1f + (size_t)m*DD + n, geluf(s4[r] + b1v));
        }
      }
      postf(bfl + bid*32, ep);
    }
    float gv[3], cxv[3];
    if (bid < 16){
      #pragma unroll
      for (int j = 0; j < 3; j++){
        size_t o2 = ((size_t)t*16 + bid)*DD + tid + j*256;
        gv[j] = gctxT[o2]; cxv[j] = ctxT[o2];
      }
    }
    // ==== stage C
    if (bid >= 48 && bid < 72){
      waitf(bfl, 48, ep);
      const int u = wid >> 1, kh = wid & 1;
      const int k0 = kh*384 + kb*8;
      const f16* ap = c1f + (size_t)l15*DD + k0;
      const int row = u*16 + l15, rowoff = row*1536, sw = (row&7)<<4;
      f32x4 a = {0.f,0.f,0.f,0.f};
      float sq = 0.f;
      #pragma unroll
      for (int b = 0; b < 12; b++){
        int wb = (rowoff + (k0 + b*32)*2) ^ sw;
        f16x8 vb = *(const f16x8*)(smem + 49152 + wb);
        f16x8 va = ld_act16h(ap + b*32);
        a = __builtin_amdgcn_mfma_f32_16x16x32_f16(va, vb, a, 0,0,0);
        #pragma unroll
        for (int j = 0; j < 8; j++){ float xv = (float)va[j]; sq = fmaf(xv, xv, sq); }
      }
      sq += __shfl_xor(sq,16); sq += __shfl_xor(sq,32);
      if (lane < 16) normp[wid][lane] = sq;
      red_store(redbuf[wid], lane, a);
      __syncthreads();
      if ((wid & 1) == 0){
        f32x4 s4 = red_sum2(redbuf, lane, wid, wid+1);
        int n = ((bid-48)*2 + (wid>>1))*16 + l15;
        #pragma unroll
        for (int r = 0; r < 4; r++){
          int m = kb*4 + r;
          float nm = normp[wid][m] + normp[wid+1][m];
          float inv = 1.f / fmaxf(sqrtf(nm), 1e-12f);
          st_acth(gcaf + (size_t)m*DD + n, geluf(s4[r]*inv + cpb1v));
        }
      }
      postf(cfl + (bid-48)*32, ep);
    }
    // ==== stage D
    if (bid >= 72){
      waitf(cfl, 24, ep);
      const int u = wid >> 1, kh = wid & 1;
      const int k0 = kh*384 + kb*8;
      const f16* ap = gcaf + (size_t)l15*DD + k0;
      const int row = u*16 + l15, rowoff = row*1536, sw = (row&7)<<4;
      f32x4 a = {0.f,0.f,0.f,0.f};
      #pragma unroll
      for (int b = 0; b < 12; b++){
        int wb = (rowoff + (k0 + b*32)*2) ^ sw;
        f16x8 vb = *(const f16x8*)(smem + 49152 + wb);
        f16x8 va = ld_act16h(ap + b*32);
        a = __builtin_amdgcn_mfma_f32_16x16x32_f16(va, vb, a, 0,0,0);
      }
      red_store(redbuf[wid], lane, a);
      __syncthreads();
      if ((wid & 1) == 0){
        f32x4 s4 = red_sum2(redbuf, lane, wid, wid+1);
        #pragma unroll
        for (int r = 0; r < 4; r++){
          int m = kb*4 + r;
          if (n_d < 768) st_actf(cf + m*DD + n_d, s4[r] + dbv);
          else           st_actf(gpre + m*DD + (n_d - 768), s4[r] + dbv);
        }
      }
      postf(dfl + (bid-72)*32, ep);
    }
    // ==== combine
    if (bid < 16){
      waitf(dfl, 48, ep);
      int m = bid;
      float vals[3]; float s = 0.f, ss = 0.f;
      #pragma unroll
      for (int j = 0; j < 3; j++){
        int n = tid + j*256;
        float gi = gv[j] + ld_actf(gpre + m*DD + n) + gb3[j];
        float gate = 1.f/(1.f + expf(-gi));
        float v = gate*(ld_actf(cf + m*DD + n) + ld_actf(tfs + m*DD + n)) + (1.f - gate)*cxv[j];
        vals[j] = v; s += v; ss += v*v;
      }
      #pragma unroll
      for (int o2 = 1; o2 < 64; o2 <<= 1){ s += __shfl_xor(s, o2); ss += __shfl_xor(ss, o2); }
      if (lane == 0){ red[wid] = s; red[4+wid] = ss; }
      __syncthreads();
      s  = red[0]+red[1]+red[2]+red[3];
      ss = red[4]+red[5]+red[6]+red[7];
      float mean = s*(1.f/768.f), var = ss*(1.f/768.f) - mean*mean;
      float rstd = rsqrtf(var + 1e-5f);
      #pragma unroll
      for (int j = 0; j < 3; j++){
        int n = tid + j*256;
        float y = (vals[j]-mean)*rstd*og3[j] + ob3[j];
        y = fminf(5.f, fmaxf(-5.f, y));
        st_acth(hf + ((size_t)m*TT + t)*DD + n, y);
      }
      postf(mfl + m*32, ep);
    }
  }
}

// ---------------- host ----------------
extern "C" void kernel_launch(void* const* d_in, const int* in_sizes, int n_in,
                              void* d_out, int out_size, void* d_ws, size_t ws_size,
                              hipStream_t stream)
{
  (void)in_sizes; (void)n_in; (void)out_size; (void)ws_size;
  const int*   tok = (const int*)d_in[0];
  const float* emb = (const float*)d_in[1];
  const float* pos = (const float*)d_in[2];
  const float* aiw = (const float*)d_in[3];
  const float* aib = (const float*)d_in[4];
  const float* aow = (const float*)d_in[5];
  const float* aob = (const float*)d_in[6];
  const float* fw1 = (const float*)d_in[7];
  const float* fb1 = (const float*)d_in[8];
  const float* fw2 = (const float*)d_in[9];
  const float* fb2 = (const float*)d_in[10];
  const float* n1g = (const float*)d_in[11];
  const float* n1b = (const float*)d_in[12];
  const float* n2g = (const float*)d_in[13];
  const float* n2b = (const float*)d_in[14];
  const float* eng = (const float*)d_in[15];
  const float* enb = (const float*)d_in[16];
  const float* V0  = (const float*)d_in[17];
  const float* b0  = (const float*)d_in[18];
  const float* V1  = (const float*)d_in[19];
  const float* b1  = (const float*)d_in[20];
  const float* cw1 = (const float*)d_in[21];
  const float* cb1 = (const float*)d_in[22];
  const float* cw2 = (const float*)d_in[23];
  const float* cb2 = (const float*)d_in[24];
  const float* gw  = (const float*)d_in[25];
  const float* gb  = (const float*)d_in[26];
  const float* tw  = (const float*)d_in[27];
  const float* Rm  = (const float*)d_in[28];
  const float* og  = (const float*)d_in[29];
  const float* ob  = (const float*)d_in[30];
  const float* lmw = (const float*)d_in[31];
  float* out = (float*)d_out;

  char* base = (char*)d_ws; size_t off = 0;
  auto alloc = [&](size_t bytes)->void*{
    off = (off + 255) & ~(size_t)255; void* p = base + off; off += bytes; return p; };

  float* x     = (float*)alloc((size_t)MR*DD*4);
  float* qkv   = (float*)alloc((size_t)MR*2304*4);
  float* o_    = (float*)alloc((size_t)MR*DD*4);
  float* mid   = (float*)alloc((size_t)MR*2048*4);
  float* ctx   = (float*)alloc((size_t)MR*DD*4);
  float* ctxT  = (float*)alloc((size_t)MR*DD*4);
  float* V0t   = (float*)alloc((size_t)3072*768*4);
  float* cw2t  = (float*)alloc((size_t)768*768*4);
  float* ctxV0T= (float*)alloc((size_t)MR*3072*4);
  float* gctxT = (float*)alloc((size_t)MR*DD*4);
  float* bdg   = (float*)alloc(768*4);
  float2* stats= (float2*)alloc((size_t)MR*8);
  float* pfb   = (float*)alloc((size_t)4*MR*DD*4);
  f16*   WAf   = (f16*)alloc((size_t)3840*768*2);
  f16*   V1tf  = (f16*)alloc((size_t)768*3072*2);
  f16*   Wc1f  = (f16*)alloc((size_t)768*768*2);
  f16*   WDf   = (f16*)alloc((size_t)1536*768*2);
  f16*   lmw16 = (f16*)alloc((size_t)LMN*768*2);
  f16*   hf    = (f16*)alloc((size_t)MR*DD*2);
  f16*   h1f   = (f16*)alloc((size_t)16*3072*2);
  f16*   c1f   = (f16*)alloc((size_t)16*768*2);
  f16*   gcaf  = (f16*)alloc((size_t)16*768*2);
  float* cf    = (float*)alloc((size_t)16*768*4);
  float* gpre  = (float*)alloc((size_t)16*768*4);
  float* tfs   = (float*)alloc((size_t)16*768*4);
  int*   flags = (int*)alloc((size_t)512*32*4);

  k_init<<<1, 256, 0, stream>>>(flags);
  k_all<<<GRID, 256, 0, stream>>>(tok, emb, pos, aiw, aib, aow, aob,
      fw1, fb1, fw2, fb2, n1g, n1b, n2g, n2b, eng, enb,
      V0, b0, V1, b1, cw1, cb1, cw2, cb2, gw, gb, tw, Rm, og, ob, lmw,
      x, qkv, o_, mid, ctx, ctxT, V0t, cw2t, ctxV0T, gctxT, bdg, stats, pfb,
      WAf, V1tf, Wc1f, WDf, lmw16, hf, h1f, c1f, gcaf, cf, gpre, tfs, flags, out);
}